// Round 5
// baseline (511.320 us; speedup 1.0000x reference)
//
#include <hip/hip_runtime.h>
#include <hip/hip_fp16.h>
#include <cstdint>

typedef unsigned short ushort_t;
typedef _Float16 f16x8 __attribute__((ext_vector_type(8)));
typedef float f32x4 __attribute__((ext_vector_type(4)));

#define M_TOT  32768
#define K_EMB  256
#define K_CORE 512
#define ACT    12
#define AP     264   // padded A row (shorts): 264*2B=528B -> bank stride 4, 2-way = free

__device__ __forceinline__ unsigned int pack2h(float a, float b) {
    __half2 h = __floats2half2_rn(a, b);
    union { __half2 h2; unsigned int u; } v; v.h2 = h; return v.u;
}
union U4H { uint4 u; f16x8 h; };

// ---------- kernel 1: transpose+convert W1[0:256,0:1024] f32 -> W1T f16 [1024][256] ----------
__global__ __launch_bounds__(256) void transpose_k(const float* __restrict__ W1,
                                                   ushort_t* __restrict__ W1T) {
    __shared__ float tile[64][65];
    const int t = threadIdx.x;
    const int k0 = blockIdx.x * 64, n0 = blockIdx.y * 64;
    const int r = t >> 4, c4 = (t & 15) * 4;
#pragma unroll
    for (int p = 0; p < 4; ++p) {
        const int row = r + p * 16;
        const float4 v = *(const float4*)(W1 + (size_t)(k0 + row) * 1024 + n0 + c4);
        tile[row][c4 + 0] = v.x; tile[row][c4 + 1] = v.y;
        tile[row][c4 + 2] = v.z; tile[row][c4 + 3] = v.w;
    }
    __syncthreads();
#pragma unroll
    for (int p = 0; p < 4; ++p) {
        const int nrow = r + p * 16;
        uint2 o;
        o.x = pack2h(tile[c4 + 0][nrow], tile[c4 + 1][nrow]);
        o.y = pack2h(tile[c4 + 2][nrow], tile[c4 + 3][nrow]);
        *(uint2*)(W1T + (size_t)(n0 + nrow) * 256 + k0 + c4) = o;
    }
}

// ---------- kernel 2: cp[b][n] = b1[n] + sum_k core[b][k]*W1[256+k][n] (exact f32) ----------
__global__ __launch_bounds__(256) void corepart_k(const float* __restrict__ core,
                                                  const float* __restrict__ W1,
                                                  const float* __restrict__ b1,
                                                  float* __restrict__ cp) {
    const int b = blockIdx.y;
    const int n = blockIdx.x * 256 + threadIdx.x;
    float s = b1[n];
    const float* cr = core + b * K_CORE;
    const float* wp = W1 + (size_t)K_EMB * 1024 + n;
#pragma unroll 8
    for (int k = 0; k < K_CORE; ++k)
        s += cr[k] * wp[(size_t)k * 1024];
    cp[b * 1024 + n] = s;
}

// ---------- kernel 3 (fused, barrier-free K-loop) ----------
// Block = 32 m-rows. A strip f16 in LDS once. B frags from global (L2) with depth-2
// register pipeline. 4 waves side-by-side in n (32 cols each), loop 8 n-tiles of 128.
// h -> out1 f32; logits in regs -> shfl+LDS reduce -> softmax -> out0.
__global__ __launch_bounds__(256, 4) void fused_k(const float* __restrict__ emb,
                                                  const ushort_t* __restrict__ w1t,
                                                  const float* __restrict__ cp,
                                                  const float* __restrict__ W2,
                                                  const float* __restrict__ b2,
                                                  const int* __restrict__ nr_units,
                                                  const int* __restrict__ nr_flags,
                                                  float* __restrict__ out0,
                                                  float* __restrict__ out1) {
    __shared__ __align__(16) ushort_t Af[32 * AP];     // ~16.9 KB
    __shared__ __align__(16) float parts[4][32][ACT];  // 6 KB

    const int t = threadIdx.x;
    const int w = t >> 6, L = t & 63;
    const int lane16 = L & 15, qd = L >> 4;
    const int m0 = blockIdx.x * 32;
    const int bb = m0 >> 9;

    // ---- stage A strip once: 32x256 f32 -> f16 LDS (coalesced float4) ----
    const float* gA = emb + (size_t)m0 * K_EMB;
#pragma unroll
    for (int j = 0; j < 8; ++j) {
        const int f = j * 256 + t;              // float4 index
        const float4 v = *(const float4*)(gA + f * 4);
        const int row = f >> 6, col = (f & 63) * 4;
        uint2 o; o.x = pack2h(v.x, v.y); o.y = pack2h(v.z, v.w);
        *(uint2*)&Af[row * AP + col] = o;
    }
    __syncthreads();

    // ---- accumulators ----
    f32x4 acc[2][2];
#pragma unroll
    for (int mi = 0; mi < 2; ++mi)
#pragma unroll
        for (int ni = 0; ni < 2; ++ni) acc[mi][ni] = (f32x4){0.f, 0.f, 0.f, 0.f};
    f32x4 la_a[8], la_b[8], la_c[8];   // 8 rows x 12 acts per lane
#pragma unroll
    for (int i = 0; i < 8; ++i) {
        la_a[i] = (f32x4){0.f, 0.f, 0.f, 0.f};
        la_b[i] = (f32x4){0.f, 0.f, 0.f, 0.f};
        la_c[i] = (f32x4){0.f, 0.f, 0.f, 0.f};
    }

    // ---- B frag addressing: nr = nt*128 + w*32 + ni*16 + lane16, k = ks*32 + qd*8 ----
    const ushort_t* gB = w1t + (size_t)(w * 32 + lane16) * K_EMB + qd * 8;
#define BOFF(IT, NI) ((((IT) >> 3) * 128 + (NI) * 16) * K_EMB + ((IT) & 7) * 32)

    uint4 bp[2][2];
    bp[0][0] = *(const uint4*)(gB + BOFF(0, 0));
    bp[0][1] = *(const uint4*)(gB + BOFF(0, 1));
    bp[1][0] = *(const uint4*)(gB + BOFF(1, 0));
    bp[1][1] = *(const uint4*)(gB + BOFF(1, 1));

#pragma unroll 8
    for (int it = 0; it < 64; ++it) {
        const int ks = it & 7;
        U4H b0, b1; b0.u = bp[it & 1][0]; b1.u = bp[it & 1][1];
        if (it + 2 < 64) {
            bp[it & 1][0] = *(const uint4*)(gB + BOFF(it + 2, 0));
            bp[it & 1][1] = *(const uint4*)(gB + BOFF(it + 2, 1));
        }
        f16x8 af0 = *(const f16x8*)&Af[(lane16)      * AP + ks * 32 + qd * 8];
        f16x8 af1 = *(const f16x8*)&Af[(16 + lane16) * AP + ks * 32 + qd * 8];
        acc[0][0] = __builtin_amdgcn_mfma_f32_16x16x32_f16(af0, b0.h, acc[0][0], 0, 0, 0);
        acc[0][1] = __builtin_amdgcn_mfma_f32_16x16x32_f16(af0, b1.h, acc[0][1], 0, 0, 0);
        acc[1][0] = __builtin_amdgcn_mfma_f32_16x16x32_f16(af1, b0.h, acc[1][0], 0, 0, 0);
        acc[1][1] = __builtin_amdgcn_mfma_f32_16x16x32_f16(af1, b1.h, acc[1][1], 0, 0, 0);

        if (ks == 7) {
            // ---- per n-tile epilogue: +cp, relu, store h, logit partials ----
            const int nt = it >> 3;
            float cpv[2]; f32x4 w2a[2], w2b[2], w2c[2];
#pragma unroll
            for (int ni = 0; ni < 2; ++ni) {
                const int cg = nt * 128 + w * 32 + ni * 16 + lane16;
                cpv[ni] = cp[bb * 1024 + cg];
                const f32x4* wp = (const f32x4*)(W2 + (size_t)cg * ACT);
                w2a[ni] = wp[0]; w2b[ni] = wp[1]; w2c[ni] = wp[2];
            }
#pragma unroll
            for (int mi = 0; mi < 2; ++mi) {
#pragma unroll
                for (int r = 0; r < 4; ++r) {
                    const size_t m = (size_t)(m0 + mi * 16 + qd * 4 + r);
                    float* orow = out1 + m * 1024 + nt * 128 + w * 32 + lane16;
#pragma unroll
                    for (int ni = 0; ni < 2; ++ni) {
                        float v = acc[mi][ni][r] + cpv[ni];
                        v = v > 0.f ? v : 0.f;
                        orow[ni * 16] = v;
                        la_a[mi * 4 + r] += w2a[ni] * v;
                        la_b[mi * 4 + r] += w2b[ni] * v;
                        la_c[mi * 4 + r] += w2c[ni] * v;
                    }
                }
#pragma unroll
                for (int ni = 0; ni < 2; ++ni) acc[mi][ni] = (f32x4){0.f, 0.f, 0.f, 0.f};
            }
        }
    }
#undef BOFF

    // ---- reduce logit partials over lane16 within wave ----
#pragma unroll
    for (int i = 0; i < 8; ++i)
#pragma unroll
        for (int s = 1; s < 16; s <<= 1)
#pragma unroll
            for (int j = 0; j < 4; ++j) {
                la_a[i][j] += __shfl_xor(la_a[i][j], s, 64);
                la_b[i][j] += __shfl_xor(la_b[i][j], s, 64);
                la_c[i][j] += __shfl_xor(la_c[i][j], s, 64);
            }
    if (lane16 == 0) {
#pragma unroll
        for (int i = 0; i < 8; ++i) {
            const int row = (i >> 2) * 16 + qd * 4 + (i & 3);
            f32x4* p = (f32x4*)&parts[w][row][0];
            p[0] = la_a[i]; p[1] = la_b[i]; p[2] = la_c[i];
        }
    }
    __syncthreads();

    // ---- softmax + range mask, thread per row ----
    if (t < 32) {
        float lg[ACT];
#pragma unroll
        for (int a = 0; a < ACT; ++a)
            lg[a] = parts[0][t][a] + parts[1][t][a] + parts[2][t][a] + parts[3][t][a] + b2[a];
        float mx = lg[0];
#pragma unroll
        for (int a = 1; a < ACT; ++a) mx = fmaxf(mx, lg[a]);
        float s = 0.f;
#pragma unroll
        for (int a = 0; a < ACT; ++a) { lg[a] = __expf(lg[a] - mx); s += lg[a]; }
        const float inv = 1.f / s;
        const int m = m0 + t;
        const int u = m & 511;
        const float msk = (u >= nr_flags[bb] && u < nr_units[bb]) ? 1.0f : 1e-9f;
        f32x4* op = (f32x4*)(out0 + (size_t)m * ACT);
        f32x4 o0, o1, o2;
#pragma unroll
        for (int j = 0; j < 4; ++j) {
            o0[j] = lg[j] * inv * msk;
            o1[j] = lg[j + 4] * inv * msk;
            o2[j] = lg[j + 8] * inv * msk;
        }
        op[0] = o0; op[1] = o1; op[2] = o2;
    }
}

extern "C" void kernel_launch(void* const* d_in, const int* in_sizes, int n_in,
                              void* d_out, int out_size, void* d_ws, size_t ws_size,
                              hipStream_t stream) {
    const float* core   = (const float*)d_in[0];
    const float* emb    = (const float*)d_in[1];
    const int* nr_units = (const int*)d_in[2];
    const int* nr_flags = (const int*)d_in[3];
    const float* W1     = (const float*)d_in[4];
    const float* b1     = (const float*)d_in[5];
    const float* W2     = (const float*)d_in[6];
    const float* b2     = (const float*)d_in[7];

    float* out0 = (float*)d_out;                       // probs [32768*12] f32
    float* out1 = out0 + (size_t)M_TOT * ACT;          // embedding [32768*1024] f32

    ushort_t* w1t = (ushort_t*)d_ws;                   // f16 [1024][256] = 512 KB
    float* cp = (float*)((char*)d_ws + (size_t)1024 * 256 * 2); // [64][1024] f32

    transpose_k<<<dim3(4, 16), 256, 0, stream>>>(W1, w1t);
    corepart_k<<<dim3(4, 64), 256, 0, stream>>>(core, W1, b1, cp);
    fused_k<<<dim3(1024), 256, 0, stream>>>(emb, w1t, cp, W2, b2, nr_units, nr_flags, out0, out1);
}

// Round 6
// 272.066 us; speedup vs baseline: 1.8794x; 1.8794x over previous
//
#include <hip/hip_runtime.h>
#include <hip/hip_fp16.h>
#include <cstdint>

typedef unsigned short ushort_t;
typedef _Float16 f16x8 __attribute__((ext_vector_type(8)));
typedef float f32x4 __attribute__((ext_vector_type(4)));

#define M_TOT  32768
#define K_EMB  256
#define K_CORE 512
#define ACT    12
#define AP     264   // padded A row (shorts): 132 dwords -> +4 banks/row -> uniform b128 access

__device__ __forceinline__ unsigned int pack2h(float a, float b) {
    __half2 h = __floats2half2_rn(a, b);
    union { __half2 h2; unsigned int u; } v; v.h2 = h; return v.u;
}
union U4H { uint4 u; f16x8 h; };

// ---------- kernel 1: transpose+convert W1[0:256,0:1024] f32 -> W1T f16 [1024][256] ----------
__global__ __launch_bounds__(256) void transpose_k(const float* __restrict__ W1,
                                                   ushort_t* __restrict__ W1T) {
    __shared__ float tile[64][65];
    const int t = threadIdx.x;
    const int k0 = blockIdx.x * 64, n0 = blockIdx.y * 64;
    const int r = t >> 4, c4 = (t & 15) * 4;
#pragma unroll
    for (int p = 0; p < 4; ++p) {
        const int row = r + p * 16;
        const float4 v = *(const float4*)(W1 + (size_t)(k0 + row) * 1024 + n0 + c4);
        tile[row][c4 + 0] = v.x; tile[row][c4 + 1] = v.y;
        tile[row][c4 + 2] = v.z; tile[row][c4 + 3] = v.w;
    }
    __syncthreads();
#pragma unroll
    for (int p = 0; p < 4; ++p) {
        const int nrow = r + p * 16;
        uint2 o;
        o.x = pack2h(tile[c4 + 0][nrow], tile[c4 + 1][nrow]);
        o.y = pack2h(tile[c4 + 2][nrow], tile[c4 + 3][nrow]);
        *(uint2*)(W1T + (size_t)(n0 + nrow) * 256 + k0 + c4) = o;
    }
}

// ---------- kernel 2: cp[b][n] = b1[n] + sum_k core[b][k]*W1[256+k][n] (exact f32) ----------
__global__ __launch_bounds__(256) void corepart_k(const float* __restrict__ core,
                                                  const float* __restrict__ W1,
                                                  const float* __restrict__ b1,
                                                  float* __restrict__ cp) {
    const int b = blockIdx.y;
    const int n = blockIdx.x * 256 + threadIdx.x;
    float s = b1[n];
    const float* cr = core + b * K_CORE;
    const float* wp = W1 + (size_t)K_EMB * 1024 + n;
#pragma unroll 8
    for (int k = 0; k < K_CORE; ++k)
        s += cr[k] * wp[(size_t)k * 1024];
    cp[b * 1024 + n] = s;
}

// ---------- kernel 3 (fused, barrier-free K-loop) ----------
// Block = 32 m-rows. A strip f16 in LDS once. B frags from global (L2) with depth-4
// register pipeline. 4 waves side-by-side in n (32 cols each), loop 8 n-tiles of 128.
// h -> out1 f32; logits in regs -> shfl+LDS reduce -> softmax -> out0.
// NOTE: launch_bounds(256,2): (256,4) capped VGPRs at 64 -> spilled la_* to scratch
// (867 MB WRITE / 622 MB FETCH in r5). 2 blocks/CU is fine: no barriers in K-loop.
__global__ __launch_bounds__(256, 2) void fused_k(const float* __restrict__ emb,
                                                  const ushort_t* __restrict__ w1t,
                                                  const float* __restrict__ cp,
                                                  const float* __restrict__ W2,
                                                  const float* __restrict__ b2,
                                                  const int* __restrict__ nr_units,
                                                  const int* __restrict__ nr_flags,
                                                  float* __restrict__ out0,
                                                  float* __restrict__ out1) {
    __shared__ __align__(16) ushort_t Af[32 * AP];     // ~16.9 KB
    __shared__ __align__(16) float parts[4][32][ACT];  // 6 KB

    const int t = threadIdx.x;
    const int w = t >> 6, L = t & 63;
    const int lane16 = L & 15, qd = L >> 4;
    const int m0 = blockIdx.x * 32;
    const int bb = m0 >> 9;

    // ---- stage A strip once: 32x256 f32 -> f16 LDS (coalesced float4) ----
    const float* gA = emb + (size_t)m0 * K_EMB;
#pragma unroll
    for (int j = 0; j < 8; ++j) {
        const int f = j * 256 + t;              // float4 index
        const float4 v = *(const float4*)(gA + f * 4);
        const int row = f >> 6, col = (f & 63) * 4;
        uint2 o; o.x = pack2h(v.x, v.y); o.y = pack2h(v.z, v.w);
        *(uint2*)&Af[row * AP + col] = o;
    }
    __syncthreads();

    // ---- accumulators ----
    f32x4 acc[2][2];
#pragma unroll
    for (int mi = 0; mi < 2; ++mi)
#pragma unroll
        for (int ni = 0; ni < 2; ++ni) acc[mi][ni] = (f32x4){0.f, 0.f, 0.f, 0.f};
    f32x4 la_a[8], la_b[8], la_c[8];   // 8 rows x 12 acts per lane
#pragma unroll
    for (int i = 0; i < 8; ++i) {
        la_a[i] = (f32x4){0.f, 0.f, 0.f, 0.f};
        la_b[i] = (f32x4){0.f, 0.f, 0.f, 0.f};
        la_c[i] = (f32x4){0.f, 0.f, 0.f, 0.f};
    }

    // ---- B frag addressing: nr = nt*128 + w*32 + ni*16 + lane16, k = ks*32 + qd*8 ----
    const ushort_t* gB = w1t + (size_t)(w * 32 + lane16) * K_EMB + qd * 8;
#define BOFF(IT, NI) ((((IT) >> 3) * 128 + (NI) * 16) * K_EMB + ((IT) & 7) * 32)

    uint4 bp[4][2];   // depth-4 register pipeline
#pragma unroll
    for (int d = 0; d < 4; ++d) {
        bp[d][0] = *(const uint4*)(gB + BOFF(d, 0));
        bp[d][1] = *(const uint4*)(gB + BOFF(d, 1));
    }

#pragma unroll 8
    for (int it = 0; it < 64; ++it) {
        const int ks = it & 7;
        U4H b0, b1; b0.u = bp[it & 3][0]; b1.u = bp[it & 3][1];
        if (it + 4 < 64) {
            bp[it & 3][0] = *(const uint4*)(gB + BOFF(it + 4, 0));
            bp[it & 3][1] = *(const uint4*)(gB + BOFF(it + 4, 1));
        }
        f16x8 af0 = *(const f16x8*)&Af[(lane16)      * AP + ks * 32 + qd * 8];
        f16x8 af1 = *(const f16x8*)&Af[(16 + lane16) * AP + ks * 32 + qd * 8];
        acc[0][0] = __builtin_amdgcn_mfma_f32_16x16x32_f16(af0, b0.h, acc[0][0], 0, 0, 0);
        acc[0][1] = __builtin_amdgcn_mfma_f32_16x16x32_f16(af0, b1.h, acc[0][1], 0, 0, 0);
        acc[1][0] = __builtin_amdgcn_mfma_f32_16x16x32_f16(af1, b0.h, acc[1][0], 0, 0, 0);
        acc[1][1] = __builtin_amdgcn_mfma_f32_16x16x32_f16(af1, b1.h, acc[1][1], 0, 0, 0);

        if (ks == 7) {
            // ---- per n-tile epilogue: +cp, relu, store h, logit partials ----
            const int nt = it >> 3;
            float cpv[2]; f32x4 w2a[2], w2b[2], w2c[2];
#pragma unroll
            for (int ni = 0; ni < 2; ++ni) {
                const int cg = nt * 128 + w * 32 + ni * 16 + lane16;
                cpv[ni] = cp[bb * 1024 + cg];
                const f32x4* wp = (const f32x4*)(W2 + (size_t)cg * ACT);
                w2a[ni] = wp[0]; w2b[ni] = wp[1]; w2c[ni] = wp[2];
            }
#pragma unroll
            for (int mi = 0; mi < 2; ++mi) {
#pragma unroll
                for (int r = 0; r < 4; ++r) {
                    const size_t m = (size_t)(m0 + mi * 16 + qd * 4 + r);
                    float* orow = out1 + m * 1024 + nt * 128 + w * 32 + lane16;
#pragma unroll
                    for (int ni = 0; ni < 2; ++ni) {
                        float v = acc[mi][ni][r] + cpv[ni];
                        v = v > 0.f ? v : 0.f;
                        orow[ni * 16] = v;
                        la_a[mi * 4 + r] += w2a[ni] * v;
                        la_b[mi * 4 + r] += w2b[ni] * v;
                        la_c[mi * 4 + r] += w2c[ni] * v;
                    }
                }
#pragma unroll
                for (int ni = 0; ni < 2; ++ni) acc[mi][ni] = (f32x4){0.f, 0.f, 0.f, 0.f};
            }
        }
    }
#undef BOFF

    // ---- reduce logit partials over lane16 within wave ----
#pragma unroll
    for (int i = 0; i < 8; ++i)
#pragma unroll
        for (int s = 1; s < 16; s <<= 1)
#pragma unroll
            for (int j = 0; j < 4; ++j) {
                la_a[i][j] += __shfl_xor(la_a[i][j], s, 64);
                la_b[i][j] += __shfl_xor(la_b[i][j], s, 64);
                la_c[i][j] += __shfl_xor(la_c[i][j], s, 64);
            }
    if (lane16 == 0) {
#pragma unroll
        for (int i = 0; i < 8; ++i) {
            const int row = (i >> 2) * 16 + qd * 4 + (i & 3);
            f32x4* p = (f32x4*)&parts[w][row][0];
            p[0] = la_a[i]; p[1] = la_b[i]; p[2] = la_c[i];
        }
    }
    __syncthreads();

    // ---- softmax + range mask, thread per row ----
    if (t < 32) {
        float lg[ACT];
#pragma unroll
        for (int a = 0; a < ACT; ++a)
            lg[a] = parts[0][t][a] + parts[1][t][a] + parts[2][t][a] + parts[3][t][a] + b2[a];
        float mx = lg[0];
#pragma unroll
        for (int a = 1; a < ACT; ++a) mx = fmaxf(mx, lg[a]);
        float s = 0.f;
#pragma unroll
        for (int a = 0; a < ACT; ++a) { lg[a] = __expf(lg[a] - mx); s += lg[a]; }
        const float inv = 1.f / s;
        const int m = m0 + t;
        const int u = m & 511;
        const float msk = (u >= nr_flags[bb] && u < nr_units[bb]) ? 1.0f : 1e-9f;
        f32x4* op = (f32x4*)(out0 + (size_t)m * ACT);
        f32x4 o0, o1, o2;
#pragma unroll
        for (int j = 0; j < 4; ++j) {
            o0[j] = lg[j] * inv * msk;
            o1[j] = lg[j + 4] * inv * msk;
            o2[j] = lg[j + 8] * inv * msk;
        }
        op[0] = o0; op[1] = o1; op[2] = o2;
    }
}

extern "C" void kernel_launch(void* const* d_in, const int* in_sizes, int n_in,
                              void* d_out, int out_size, void* d_ws, size_t ws_size,
                              hipStream_t stream) {
    const float* core   = (const float*)d_in[0];
    const float* emb    = (const float*)d_in[1];
    const int* nr_units = (const int*)d_in[2];
    const int* nr_flags = (const int*)d_in[3];
    const float* W1     = (const float*)d_in[4];
    const float* b1     = (const float*)d_in[5];
    const float* W2     = (const float*)d_in[6];
    const float* b2     = (const float*)d_in[7];

    float* out0 = (float*)d_out;                       // probs [32768*12] f32
    float* out1 = out0 + (size_t)M_TOT * ACT;          // embedding [32768*1024] f32

    ushort_t* w1t = (ushort_t*)d_ws;                   // f16 [1024][256] = 512 KB
    float* cp = (float*)((char*)d_ws + (size_t)1024 * 256 * 2); // [64][1024] f32

    transpose_k<<<dim3(4, 16), 256, 0, stream>>>(W1, w1t);
    corepart_k<<<dim3(4, 64), 256, 0, stream>>>(core, W1, b1, cp);
    fused_k<<<dim3(1024), 256, 0, stream>>>(emb, w1t, cp, W2, b2, nr_units, nr_flags, out0, out1);
}